// Round 9
// baseline (13180.356 us; speedup 1.0000x reference)
//
#include <hip/hip_runtime.h>
#include <math.h>

#define DEV __device__ __forceinline__

DEV float sigmoid_(float x) { return 1.0f / (1.0f + __expf(-x)); }
DEV float tanh_(float x) {
    float e = __expf(2.0f * x);
    return 1.0f - 2.0f / (e + 1.0f);
}

// ---------------------------------------------------------------------------
// Device-scope grid barrier (monotonic counter, one arrive per block).
// Requires all gridDim.x blocks co-resident. __syncthreads() drains each
// wave's stores to L2; thread0's __threadfence() (agent fence) writes L2
// back to device scope before arrival; acquire fence after spin.
// ---------------------------------------------------------------------------
DEV void gbar(unsigned* cnt, unsigned target) {
    __syncthreads();
    if (threadIdx.x == 0) {
        __threadfence();
        __hip_atomic_fetch_add(cnt, 1u, __ATOMIC_RELEASE, __HIP_MEMORY_SCOPE_AGENT);
        while (__hip_atomic_load(cnt, __ATOMIC_ACQUIRE, __HIP_MEMORY_SCOPE_AGENT)
               < target) {
            __builtin_amdgcn_s_sleep(1);
        }
        __threadfence();
    }
    __syncthreads();
}

// ---------------------------------------------------------------------------
// zx_k: z_x = bias + conv3x3(x_t) for a time chunk.
// oc uniform per block -> weight loads scalar. zx: [B,TcMax,4,hid,H,W]
// ---------------------------------------------------------------------------
template<int TPB, int OCL, int RPT>
__global__ __launch_bounds__(TPB) void zx_k(
    const float* __restrict__ xin, const float* __restrict__ w,
    const float* __restrict__ bias, float* __restrict__ zx,
    int t0, int TcAct, int TcMax, int B, int T, int Cin, int Ctot,
    int hid, int H, int W, int nOcg, int BPP)
{
    const int HW = H * W;
    int blk   = blockIdx.x;
    int chunk = blk % BPP;
    int ocg   = (blk / BPP) % nOcg;
    int tc    = (blk / (BPP * nOcg)) % TcAct;
    int b     = blk / (BPP * nOcg * TcAct);
    int oc0   = ocg * OCL;

    int p    = threadIdx.x;
    int col  = p % W;
    int rowg = p / W;
    int rpc  = (TPB / W) * RPT;
    int y0   = chunk * rpc + rowg * RPT;

    int   off[RPT + 2][3];
    float msk[RPT + 2][3];
    #pragma unroll
    for (int dy = 0; dy < RPT + 2; ++dy) {
        int yy = y0 + dy - 1;
        #pragma unroll
        for (int dx = 0; dx < 3; ++dx) {
            int xx = col + dx - 1;
            bool ok = (yy >= 0 && yy < H && xx >= 0 && xx < W);
            off[dy][dx] = ok ? yy * W + xx : 0;
            msk[dy][dx] = ok ? 1.0f : 0.0f;
        }
    }

    float z[RPT][OCL][4];
    #pragma unroll
    for (int r = 0; r < RPT; ++r)
        #pragma unroll
        for (int j = 0; j < OCL; ++j)
            #pragma unroll
            for (int g = 0; g < 4; ++g)
                z[r][j][g] = bias[g * hid + oc0 + j];

    const float* xsl = xin + ((size_t)(b * T + t0 + tc) * Cin) * HW;
    for (int ic = 0; ic < Cin; ++ic) {
        const float* src = xsl + (size_t)ic * HW;
        float v[RPT + 2][3];
        #pragma unroll
        for (int dy = 0; dy < RPT + 2; ++dy)
            #pragma unroll
            for (int dx = 0; dx < 3; ++dx)
                v[dy][dx] = src[off[dy][dx]] * msk[dy][dx];

        #pragma unroll
        for (int j = 0; j < OCL; ++j)
            #pragma unroll
            for (int g = 0; g < 4; ++g) {
                const float* wp = w + ((size_t)(g * hid + oc0 + j) * Ctot + ic) * 9;
                #pragma unroll
                for (int k = 0; k < 9; ++k) {
                    float wv = wp[k];
                    #pragma unroll
                    for (int r = 0; r < RPT; ++r)
                        z[r][j][g] = fmaf(v[r + k / 3][k % 3], wv, z[r][j][g]);
                }
            }
    }

    size_t base = ((size_t)(b * TcMax + tc) * 4 * hid) * HW;
    #pragma unroll
    for (int r = 0; r < RPT; ++r) {
        size_t rb = base + (size_t)(y0 + r) * W + col;
        #pragma unroll
        for (int j = 0; j < OCL; ++j)
            #pragma unroll
            for (int g = 0; g < 4; ++g)
                zx[rb + (size_t)(g * hid + oc0 + j) * HW] = z[r][j][g];
    }
}

// ---------------------------------------------------------------------------
// steps_persist: runs Tc ConvLSTM timesteps in ONE launch.
// Per block: fixed (b, oc-group, spatial chunk); h-weights staged in LDS once
// (layout [ocl][ic][k][g] -> float4 broadcast reads); c held in registers.
// Grid barrier between steps. grid MUST be 512 blocks (2/CU co-resident).
// ---------------------------------------------------------------------------
template<int TPB, int OCL, int RPT, int HID>
__global__ __launch_bounds__(TPB, 2) void steps_persist(
    const float* __restrict__ zx,    // [B,TcMax,4,hid,H,W]
    const float* __restrict__ w,     // [4*hid, Ctot, 3, 3]
    float* __restrict__ hbuf,        // [B,T,hid,H,W]
    float* __restrict__ cbuf,        // [B,hid,H,W]
    unsigned* __restrict__ barcnt, unsigned barBase,
    int t0, int Tc, int TcMax, int B, int T, int Cin, int H, int W,
    int nOcg, int BPP)
{
    const int hid = HID;
    const int HW = H * W;
    const int Ctot = Cin + hid;
    __shared__ float wlds[OCL * HID * 36];   // [ocl][ic][k][g]

    int blk   = blockIdx.x;
    int chunk = blk % BPP;
    int ocg   = (blk / BPP) % nOcg;
    int b     = blk / (BPP * nOcg);
    int oc0   = ocg * OCL;

    for (int i = threadIdx.x; i < OCL * HID * 36; i += TPB) {
        int g   = i & 3;
        int k   = (i >> 2) % 9;
        int ic  = (i / 36) % HID;
        int ocl = i / (36 * HID);
        wlds[i] = w[((size_t)(g * hid + oc0 + ocl) * Ctot + Cin + ic) * 9 + k];
    }
    __syncthreads();

    int p    = threadIdx.x;
    int col  = p % W;
    int rowg = p / W;
    int rpc  = (TPB / W) * RPT;
    int y0   = chunk * rpc + rowg * RPT;

    int   off[RPT + 2][3];
    float msk[RPT + 2][3];
    #pragma unroll
    for (int dy = 0; dy < RPT + 2; ++dy) {
        int yy = y0 + dy - 1;
        #pragma unroll
        for (int dx = 0; dx < 3; ++dx) {
            int xx = col + dx - 1;
            bool ok = (yy >= 0 && yy < H && xx >= 0 && xx < W);
            off[dy][dx] = ok ? yy * W + xx : 0;
            msk[dy][dx] = ok ? 1.0f : 0.0f;
        }
    }

    // c in registers for the whole chunk
    float c[RPT][OCL];
    #pragma unroll
    for (int r = 0; r < RPT; ++r)
        #pragma unroll
        for (int j = 0; j < OCL; ++j) {
            if (t0 == 0) c[r][j] = 0.0f;
            else c[r][j] = cbuf[((size_t)b * hid + oc0 + j) * HW
                                + (size_t)(y0 + r) * W + col];
        }

    for (int s = 0; s < Tc; ++s) {
        int t = t0 + s;

        float z[RPT][OCL][4];
        size_t zbase = ((size_t)(b * TcMax + s) * 4 * hid) * HW;
        #pragma unroll
        for (int r = 0; r < RPT; ++r) {
            size_t rb = zbase + (size_t)(y0 + r) * W + col;
            #pragma unroll
            for (int j = 0; j < OCL; ++j)
                #pragma unroll
                for (int g = 0; g < 4; ++g)
                    z[r][j][g] = zx[rb + (size_t)(g * hid + oc0 + j) * HW];
        }

        if (t > 0) {
            const float* hsl = hbuf + ((size_t)(b * T + (t - 1)) * hid) * HW;
            #pragma unroll 2
            for (int ic = 0; ic < HID; ++ic) {
                const float* src = hsl + (size_t)ic * HW;
                float v[RPT + 2][3];
                #pragma unroll
                for (int dy = 0; dy < RPT + 2; ++dy)
                    #pragma unroll
                    for (int dx = 0; dx < 3; ++dx)
                        v[dy][dx] = src[off[dy][dx]] * msk[dy][dx];

                #pragma unroll
                for (int k = 0; k < 9; ++k) {
                    #pragma unroll
                    for (int j = 0; j < OCL; ++j) {
                        const float4 wv = *(const float4*)
                            &wlds[(((j * HID + ic) * 9) + k) * 4];
                        #pragma unroll
                        for (int r = 0; r < RPT; ++r) {
                            float vv = v[r + k / 3][k % 3];
                            z[r][j][0] = fmaf(vv, wv.x, z[r][j][0]);
                            z[r][j][1] = fmaf(vv, wv.y, z[r][j][1]);
                            z[r][j][2] = fmaf(vv, wv.z, z[r][j][2]);
                            z[r][j][3] = fmaf(vv, wv.w, z[r][j][3]);
                        }
                    }
                }
            }
        }

        #pragma unroll
        for (int r = 0; r < RPT; ++r) {
            int y = y0 + r;
            #pragma unroll
            for (int j = 0; j < OCL; ++j) {
                float ig = sigmoid_(z[r][j][0]);
                float fg = sigmoid_(z[r][j][1]);
                float og = sigmoid_(z[r][j][2]);
                float gg = tanh_(z[r][j][3]);
                float cn = fg * c[r][j] + ig * gg;
                c[r][j] = cn;
                hbuf[((size_t)(b * T + t) * hid + oc0 + j) * HW
                     + (size_t)y * W + col] = og * tanh_(cn);
            }
        }

        if (s < Tc - 1)
            gbar(barcnt, barBase + (unsigned)(s + 1) * gridDim.x);
    }

    #pragma unroll
    for (int r = 0; r < RPT; ++r)
        #pragma unroll
        for (int j = 0; j < OCL; ++j)
            cbuf[((size_t)b * hid + oc0 + j) * HW + (size_t)(y0 + r) * W + col]
                = c[r][j];
}

// ---------------------------------------------------------------------------
// BatchNorm stats / BN+ReLU+Pool / FC head
// ---------------------------------------------------------------------------
__global__ void bn_stats(const float* __restrict__ hbuf, float* __restrict__ stats,
                         int BT, int C, int HW)
{
    int c = blockIdx.x;
    float s = 0.0f, s2 = 0.0f;
    for (int bt = blockIdx.y; bt < BT; bt += gridDim.y) {
        const float* p = hbuf + ((size_t)bt * C + c) * HW;
        for (int i = threadIdx.x; i < HW; i += blockDim.x) {
            float v = p[i];
            s += v;
            s2 += v * v;
        }
    }
    __shared__ float ssum[256];
    __shared__ float ssq[256];
    int tid = threadIdx.x;
    ssum[tid] = s; ssq[tid] = s2;
    __syncthreads();
    for (int off = 128; off > 0; off >>= 1) {
        if (tid < off) { ssum[tid] += ssum[tid + off]; ssq[tid] += ssq[tid + off]; }
        __syncthreads();
    }
    if (tid == 0) {
        atomicAdd(&stats[2 * c + 0], ssum[0]);
        atomicAdd(&stats[2 * c + 1], ssq[0]);
    }
}

__global__ void bn_relu_pool(const float* __restrict__ hbuf,
                             const float* __restrict__ stats,
                             const float* __restrict__ gamma,
                             const float* __restrict__ beta,
                             float* __restrict__ out,
                             int BT, int C, int H, int W, float invN)
{
    int Ho = H / 2, Wo = W / 2;
    int idx = blockIdx.x * blockDim.x + threadIdx.x;
    int total = BT * C * Ho * Wo;
    if (idx >= total) return;
    int xo = idx % Wo;
    int yo = (idx / Wo) % Ho;
    int c  = (idx / (Wo * Ho)) % C;
    int bt = idx / (C * Ho * Wo);

    float mean = stats[2 * c + 0] * invN;
    float var  = stats[2 * c + 1] * invN - mean * mean;
    float sc = gamma[c] * rsqrtf(var + 1e-5f);
    float sh = beta[c] - mean * sc;

    const float* p = hbuf + ((size_t)bt * C + c) * (H * W) + (2 * yo) * W + 2 * xo;
    float a0 = fmaxf(fmaf(p[0],     sc, sh), 0.0f);
    float a1 = fmaxf(fmaf(p[1],     sc, sh), 0.0f);
    float a2 = fmaxf(fmaf(p[W],     sc, sh), 0.0f);
    float a3 = fmaxf(fmaf(p[W + 1], sc, sh), 0.0f);
    out[idx] = fmaxf(fmaxf(a0, a1), fmaxf(a2, a3));
}

__global__ __launch_bounds__(128) void fc_head(const float* __restrict__ feat,
                                               const float* __restrict__ fc1w,
                                               const float* __restrict__ fc1b,
                                               const float* __restrict__ fc2w,
                                               const float* __restrict__ fc2b,
                                               float* __restrict__ out)
{
    __shared__ float sf[1024];
    __shared__ float y1[128];
    int bt = blockIdx.x;
    const float* f = feat + (size_t)bt * 1024;
    for (int i = threadIdx.x; i < 1024; i += 128) sf[i] = f[i];
    __syncthreads();
    int k = threadIdx.x;
    float acc = fc1b[k];
    const float* wk = fc1w + (size_t)k * 1024;
    for (int d = 0; d < 1024; ++d) acc = fmaf(sf[d], wk[d], acc);
    y1[k] = fmaxf(acc, 0.0f);
    __syncthreads();
    if (k < 2) {
        float a = fc2b[k];
        const float* w2 = fc2w + k * 128;
        for (int j = 0; j < 128; ++j) a = fmaf(y1[j], w2[j], a);
        out[(size_t)bt * 2 + k] = a;
    }
}

// ---------------------------------------------------------------------------
// Host
// ---------------------------------------------------------------------------
static void launch_zx(int l, const float* in, const float* w, const float* bias,
                      float* zbuf, int t0, int TcAct, int TcMax, int B, int T,
                      int Cin, int hid, int H, int W, hipStream_t s)
{
    int Ctot = Cin + hid, HW = H * W;
    switch (l) {
        case 0: { const int TPB=256,OCL=4,RPT=2; int nOcg=hid/OCL, BPP=HW/(TPB*RPT);
            zx_k<256,4,2><<<B*TcAct*nOcg*BPP, TPB, 0, s>>>(in,w,bias,zbuf,t0,TcAct,TcMax,B,T,Cin,Ctot,hid,H,W,nOcg,BPP); } break;
        case 1: { const int TPB=256,OCL=4,RPT=2; int nOcg=hid/OCL, BPP=HW/(TPB*RPT);
            zx_k<256,4,2><<<B*TcAct*nOcg*BPP, TPB, 0, s>>>(in,w,bias,zbuf,t0,TcAct,TcMax,B,T,Cin,Ctot,hid,H,W,nOcg,BPP); } break;
        case 2: { const int TPB=256,OCL=4,RPT=1; int nOcg=hid/OCL, BPP=HW/(TPB*RPT);
            zx_k<256,4,1><<<B*TcAct*nOcg*BPP, TPB, 0, s>>>(in,w,bias,zbuf,t0,TcAct,TcMax,B,T,Cin,Ctot,hid,H,W,nOcg,BPP); } break;
        case 3: { const int TPB=64,OCL=4,RPT=1; int nOcg=hid/OCL, BPP=HW/(TPB*RPT);
            zx_k<64,4,1><<<B*TcAct*nOcg*BPP, TPB, 0, s>>>(in,w,bias,zbuf,t0,TcAct,TcMax,B,T,Cin,Ctot,hid,H,W,nOcg,BPP); } break;
    }
}

extern "C" void kernel_launch(void* const* d_in, const int* in_sizes, int n_in,
                              void* d_out, int out_size, void* d_ws, size_t ws_size,
                              hipStream_t stream)
{
    const int B = 8, T = 40;
    const float* x = (const float*)d_in[0];

    // workspace layout (floats); ~141 MB total (proven available)
    float* hbuf  = (float*)d_ws;                 // 20,971,520
    float* pbuf  = hbuf + (size_t)20971520;      //  5,242,880
    float* cbuf  = pbuf + (size_t)5242880;       //    524,288
    float* stats = cbuf + (size_t)524288;        //        128
    float* zbuf  = stats + 128;                  //  8,388,608
    unsigned* barcnt = (unsigned*)(zbuf + 8388608);

    hipMemsetAsync(barcnt, 0, sizeof(unsigned), stream);
    unsigned barBase = 0;

    struct LCfg { int Cin, hid, H, W, Tc; };
    const LCfg L[4] = { {1, 16, 64, 64, 4}, {16, 32, 32, 32, 8},
                        {32, 64, 16, 16, 16}, {64, 64, 8, 8, 40} };

    const float* in = x;
    for (int l = 0; l < 4; ++l) {
        const float* w     = (const float*)d_in[1 + 4 * l];
        const float* bias  = (const float*)d_in[2 + 4 * l];
        const float* gamma = (const float*)d_in[3 + 4 * l];
        const float* beta  = (const float*)d_in[4 + 4 * l];
        const int Cin = L[l].Cin, hid = L[l].hid, H = L[l].H, W = L[l].W;
        const int HW = H * W;
        const int TcMax = L[l].Tc;

        for (int t0 = 0; t0 < T; t0 += TcMax) {
            int TcAct = (T - t0 < TcMax) ? (T - t0) : TcMax;
            launch_zx(l, in, w, bias, zbuf, t0, TcAct, TcMax, B, T, Cin, hid, H, W, stream);
            switch (l) {  // grid = 512 blocks in every config (2 blocks/CU co-resident)
                case 0: steps_persist<256,2,2,16><<<512,256,0,stream>>>(
                            zbuf,w,hbuf,cbuf,barcnt,barBase,t0,TcAct,TcMax,B,T,Cin,H,W, 8,8); break;
                case 1: steps_persist<256,2,1,32><<<512,256,0,stream>>>(
                            zbuf,w,hbuf,cbuf,barcnt,barBase,t0,TcAct,TcMax,B,T,Cin,H,W,16,4); break;
                case 2: steps_persist<256,1,1,64><<<512,256,0,stream>>>(
                            zbuf,w,hbuf,cbuf,barcnt,barBase,t0,TcAct,TcMax,B,T,Cin,H,W,64,1); break;
                case 3: steps_persist< 64,1,1,64><<<512, 64,0,stream>>>(
                            zbuf,w,hbuf,cbuf,barcnt,barBase,t0,TcAct,TcMax,B,T,Cin,H,W,64,1); break;
            }
            barBase += (unsigned)(TcAct - 1) * 512u;
        }

        hipMemsetAsync(stats, 0, 2 * hid * sizeof(float), stream);
        bn_stats<<<dim3(hid, 80), 256, 0, stream>>>(hbuf, stats, B * T, hid, HW);

        int ptotal = B * T * hid * (H / 2) * (W / 2);
        float invN = 1.0f / ((float)(B * T) * (float)HW);
        bn_relu_pool<<<(ptotal + 255) / 256, 256, 0, stream>>>(
            hbuf, stats, gamma, beta, pbuf, B * T, hid, H, W, invN);
        in = pbuf;
    }

    const float* fc1w = (const float*)d_in[17];
    const float* fc1b = (const float*)d_in[18];
    const float* fc2w = (const float*)d_in[19];
    const float* fc2b = (const float*)d_in[20];
    fc_head<<<B * T, 128, 0, stream>>>(pbuf, fc1w, fc1b, fc2w, fc2b, (float*)d_out);
}

// Round 10
// 7368.862 us; speedup vs baseline: 1.7887x; 1.7887x over previous
//
#include <hip/hip_runtime.h>
#include <math.h>

#define DEV __device__ __forceinline__

DEV float sigmoid_(float x) { return 1.0f / (1.0f + __expf(-x)); }
DEV float tanh_(float x) {
    float e = __expf(2.0f * x);
    return 1.0f - 2.0f / (e + 1.0f);
}

// ---------------------------------------------------------------------------
// zx_k (round-5, measured good): z_x = bias + conv3x3(x_t) for a time chunk.
// oc uniform per block -> weight loads scalar. zx: [B,TcMax,4,hid,H,W]
// ---------------------------------------------------------------------------
template<int TPB, int OCL, int RPT>
__global__ __launch_bounds__(TPB) void zx_k(
    const float* __restrict__ xin, const float* __restrict__ w,
    const float* __restrict__ bias, float* __restrict__ zx,
    int t0, int TcAct, int TcMax, int B, int T, int Cin, int Ctot,
    int hid, int H, int W, int nOcg, int BPP)
{
    const int HW = H * W;
    int blk   = blockIdx.x;
    int chunk = blk % BPP;
    int ocg   = (blk / BPP) % nOcg;
    int tc    = (blk / (BPP * nOcg)) % TcAct;
    int b     = blk / (BPP * nOcg * TcAct);
    int oc0   = ocg * OCL;

    int p    = threadIdx.x;
    int col  = p % W;
    int rowg = p / W;
    int rpc  = (TPB / W) * RPT;
    int y0   = chunk * rpc + rowg * RPT;

    int   off[RPT + 2][3];
    float msk[RPT + 2][3];
    #pragma unroll
    for (int dy = 0; dy < RPT + 2; ++dy) {
        int yy = y0 + dy - 1;
        #pragma unroll
        for (int dx = 0; dx < 3; ++dx) {
            int xx = col + dx - 1;
            bool ok = (yy >= 0 && yy < H && xx >= 0 && xx < W);
            off[dy][dx] = ok ? yy * W + xx : 0;
            msk[dy][dx] = ok ? 1.0f : 0.0f;
        }
    }

    float z[RPT][OCL][4];
    #pragma unroll
    for (int r = 0; r < RPT; ++r)
        #pragma unroll
        for (int j = 0; j < OCL; ++j)
            #pragma unroll
            for (int g = 0; g < 4; ++g)
                z[r][j][g] = bias[g * hid + oc0 + j];

    const float* xsl = xin + ((size_t)(b * T + t0 + tc) * Cin) * HW;
    for (int ic = 0; ic < Cin; ++ic) {
        const float* src = xsl + (size_t)ic * HW;
        float v[RPT + 2][3];
        #pragma unroll
        for (int dy = 0; dy < RPT + 2; ++dy)
            #pragma unroll
            for (int dx = 0; dx < 3; ++dx)
                v[dy][dx] = src[off[dy][dx]] * msk[dy][dx];

        #pragma unroll
        for (int j = 0; j < OCL; ++j)
            #pragma unroll
            for (int g = 0; g < 4; ++g) {
                const float* wp = w + ((size_t)(g * hid + oc0 + j) * Ctot + ic) * 9;
                #pragma unroll
                for (int k = 0; k < 9; ++k) {
                    float wv = wp[k];
                    #pragma unroll
                    for (int r = 0; r < RPT; ++r)
                        z[r][j][g] = fmaf(v[r + k / 3][k % 3], wv, z[r][j][g]);
                }
            }
    }

    size_t base = ((size_t)(b * TcMax + tc) * 4 * hid) * HW;
    #pragma unroll
    for (int r = 0; r < RPT; ++r) {
        size_t rb = base + (size_t)(y0 + r) * W + col;
        #pragma unroll
        for (int j = 0; j < OCL; ++j)
            #pragma unroll
            for (int g = 0; g < 4; ++g)
                zx[rb + (size_t)(g * hid + oc0 + j) * HW] = z[r][j][g];
    }
}

// ---------------------------------------------------------------------------
// step_k: one ConvLSTM timestep (per-step launch, no grid barrier).
// z = zx(precomputed) + conv3x3(h_{t-1}); gates; state update.
// h-weights staged in LDS as [ocl][ic][k][g] -> one broadcast ds_read_b128
// feeds RPT*4 FMAs. Every layer config gives exactly 512 blocks.
// ---------------------------------------------------------------------------
template<int TPB, int OCL, int RPT, int HID>
__global__ __launch_bounds__(TPB) void step_k(
    const float* __restrict__ zx,    // [B,TcMax,4,hid,H,W]
    const float* __restrict__ w,     // [4*hid, Ctot, 3, 3]
    float* __restrict__ hbuf,        // [B,T,hid,H,W]
    float* __restrict__ cbuf,        // [B,hid,H,W]
    int t, int tc, int TcMax, int B, int T, int Cin, int H, int W,
    int nOcg, int BPP)
{
    const int hid = HID;
    const int HW = H * W;
    const int Ctot = Cin + hid;
    alignas(16) __shared__ float wlds[OCL * HID * 36];   // [ocl][ic][k][g]

    int blk   = blockIdx.x;
    int chunk = blk % BPP;
    int ocg   = (blk / BPP) % nOcg;
    int b     = blk / (BPP * nOcg);
    int oc0   = ocg * OCL;

    if (t > 0) {
        for (int i = threadIdx.x; i < OCL * HID * 36; i += TPB) {
            int g   = i & 3;
            int k   = (i >> 2) % 9;
            int ic  = (i / 36) % HID;
            int ocl = i / (36 * HID);
            wlds[i] = w[((size_t)(g * hid + oc0 + ocl) * Ctot + Cin + ic) * 9 + k];
        }
        __syncthreads();
    }

    int p    = threadIdx.x;
    int col  = p % W;
    int rowg = p / W;
    int rpc  = (TPB / W) * RPT;
    int y0   = chunk * rpc + rowg * RPT;

    float z[RPT][OCL][4];
    size_t zbase = ((size_t)(b * TcMax + tc) * 4 * hid) * HW;
    #pragma unroll
    for (int r = 0; r < RPT; ++r) {
        size_t rb = zbase + (size_t)(y0 + r) * W + col;
        #pragma unroll
        for (int j = 0; j < OCL; ++j)
            #pragma unroll
            for (int g = 0; g < 4; ++g)
                z[r][j][g] = zx[rb + (size_t)(g * hid + oc0 + j) * HW];
    }

    if (t > 0) {
        int   off[RPT + 2][3];
        float msk[RPT + 2][3];
        #pragma unroll
        for (int dy = 0; dy < RPT + 2; ++dy) {
            int yy = y0 + dy - 1;
            #pragma unroll
            for (int dx = 0; dx < 3; ++dx) {
                int xx = col + dx - 1;
                bool ok = (yy >= 0 && yy < H && xx >= 0 && xx < W);
                off[dy][dx] = ok ? yy * W + xx : 0;
                msk[dy][dx] = ok ? 1.0f : 0.0f;
            }
        }

        const float* hsl = hbuf + ((size_t)(b * T + (t - 1)) * hid) * HW;
        #pragma unroll 2
        for (int ic = 0; ic < HID; ++ic) {
            const float* src = hsl + (size_t)ic * HW;
            float v[RPT + 2][3];
            #pragma unroll
            for (int dy = 0; dy < RPT + 2; ++dy)
                #pragma unroll
                for (int dx = 0; dx < 3; ++dx)
                    v[dy][dx] = src[off[dy][dx]] * msk[dy][dx];

            #pragma unroll
            for (int k = 0; k < 9; ++k) {
                #pragma unroll
                for (int j = 0; j < OCL; ++j) {
                    const float4 wv = *(const float4*)
                        &wlds[(((j * HID + ic) * 9) + k) * 4];
                    #pragma unroll
                    for (int r = 0; r < RPT; ++r) {
                        float vv = v[r + k / 3][k % 3];
                        z[r][j][0] = fmaf(vv, wv.x, z[r][j][0]);
                        z[r][j][1] = fmaf(vv, wv.y, z[r][j][1]);
                        z[r][j][2] = fmaf(vv, wv.z, z[r][j][2]);
                        z[r][j][3] = fmaf(vv, wv.w, z[r][j][3]);
                    }
                }
            }
        }
    }

    #pragma unroll
    for (int r = 0; r < RPT; ++r) {
        int y = y0 + r;
        #pragma unroll
        for (int j = 0; j < OCL; ++j) {
            int oc = oc0 + j;
            size_t ci = ((size_t)b * hid + oc) * HW + (size_t)y * W + col;
            float cprev = (t == 0) ? 0.0f : cbuf[ci];
            float ig = sigmoid_(z[r][j][0]);
            float fg = sigmoid_(z[r][j][1]);
            float og = sigmoid_(z[r][j][2]);
            float gg = tanh_(z[r][j][3]);
            float cn = fg * cprev + ig * gg;
            cbuf[ci] = cn;
            hbuf[((size_t)(b * T + t) * hid + oc) * HW + (size_t)y * W + col]
                = og * tanh_(cn);
        }
    }
}

// ---------------------------------------------------------------------------
// BatchNorm stats / BN+ReLU+Pool / FC head
// ---------------------------------------------------------------------------
__global__ void bn_stats(const float* __restrict__ hbuf, float* __restrict__ stats,
                         int BT, int C, int HW)
{
    int c = blockIdx.x;
    float s = 0.0f, s2 = 0.0f;
    for (int bt = blockIdx.y; bt < BT; bt += gridDim.y) {
        const float* p = hbuf + ((size_t)bt * C + c) * HW;
        for (int i = threadIdx.x; i < HW; i += blockDim.x) {
            float v = p[i];
            s += v;
            s2 += v * v;
        }
    }
    __shared__ float ssum[256];
    __shared__ float ssq[256];
    int tid = threadIdx.x;
    ssum[tid] = s; ssq[tid] = s2;
    __syncthreads();
    for (int off = 128; off > 0; off >>= 1) {
        if (tid < off) { ssum[tid] += ssum[tid + off]; ssq[tid] += ssq[tid + off]; }
        __syncthreads();
    }
    if (tid == 0) {
        atomicAdd(&stats[2 * c + 0], ssum[0]);
        atomicAdd(&stats[2 * c + 1], ssq[0]);
    }
}

__global__ void bn_relu_pool(const float* __restrict__ hbuf,
                             const float* __restrict__ stats,
                             const float* __restrict__ gamma,
                             const float* __restrict__ beta,
                             float* __restrict__ out,
                             int BT, int C, int H, int W, float invN)
{
    int Ho = H / 2, Wo = W / 2;
    int idx = blockIdx.x * blockDim.x + threadIdx.x;
    int total = BT * C * Ho * Wo;
    if (idx >= total) return;
    int xo = idx % Wo;
    int yo = (idx / Wo) % Ho;
    int c  = (idx / (Wo * Ho)) % C;
    int bt = idx / (C * Ho * Wo);

    float mean = stats[2 * c + 0] * invN;
    float var  = stats[2 * c + 1] * invN - mean * mean;
    float sc = gamma[c] * rsqrtf(var + 1e-5f);
    float sh = beta[c] - mean * sc;

    const float* p = hbuf + ((size_t)bt * C + c) * (H * W) + (2 * yo) * W + 2 * xo;
    float a0 = fmaxf(fmaf(p[0],     sc, sh), 0.0f);
    float a1 = fmaxf(fmaf(p[1],     sc, sh), 0.0f);
    float a2 = fmaxf(fmaf(p[W],     sc, sh), 0.0f);
    float a3 = fmaxf(fmaf(p[W + 1], sc, sh), 0.0f);
    out[idx] = fmaxf(fmaxf(a0, a1), fmaxf(a2, a3));
}

__global__ __launch_bounds__(128) void fc_head(const float* __restrict__ feat,
                                               const float* __restrict__ fc1w,
                                               const float* __restrict__ fc1b,
                                               const float* __restrict__ fc2w,
                                               const float* __restrict__ fc2b,
                                               float* __restrict__ out)
{
    __shared__ float sf[1024];
    __shared__ float y1[128];
    int bt = blockIdx.x;
    const float* f = feat + (size_t)bt * 1024;
    for (int i = threadIdx.x; i < 1024; i += 128) sf[i] = f[i];
    __syncthreads();
    int k = threadIdx.x;
    float acc = fc1b[k];
    const float* wk = fc1w + (size_t)k * 1024;
    for (int d = 0; d < 1024; ++d) acc = fmaf(sf[d], wk[d], acc);
    y1[k] = fmaxf(acc, 0.0f);
    __syncthreads();
    if (k < 2) {
        float a = fc2b[k];
        const float* w2 = fc2w + k * 128;
        for (int j = 0; j < 128; ++j) a = fmaf(y1[j], w2[j], a);
        out[(size_t)bt * 2 + k] = a;
    }
}

// ---------------------------------------------------------------------------
// Host
// ---------------------------------------------------------------------------
static void launch_zx(int l, const float* in, const float* w, const float* bias,
                      float* zbuf, int t0, int TcAct, int TcMax, int B, int T,
                      int Cin, int hid, int H, int W, hipStream_t s)
{
    int Ctot = Cin + hid, HW = H * W;
    switch (l) {
        case 0: { const int TPB=256,OCL=4,RPT=2; int nOcg=hid/OCL, BPP=HW/(TPB*RPT);
            zx_k<256,4,2><<<B*TcAct*nOcg*BPP, TPB, 0, s>>>(in,w,bias,zbuf,t0,TcAct,TcMax,B,T,Cin,Ctot,hid,H,W,nOcg,BPP); } break;
        case 1: { const int TPB=256,OCL=4,RPT=2; int nOcg=hid/OCL, BPP=HW/(TPB*RPT);
            zx_k<256,4,2><<<B*TcAct*nOcg*BPP, TPB, 0, s>>>(in,w,bias,zbuf,t0,TcAct,TcMax,B,T,Cin,Ctot,hid,H,W,nOcg,BPP); } break;
        case 2: { const int TPB=256,OCL=4,RPT=1; int nOcg=hid/OCL, BPP=HW/(TPB*RPT);
            zx_k<256,4,1><<<B*TcAct*nOcg*BPP, TPB, 0, s>>>(in,w,bias,zbuf,t0,TcAct,TcMax,B,T,Cin,Ctot,hid,H,W,nOcg,BPP); } break;
        case 3: { const int TPB=64,OCL=4,RPT=1; int nOcg=hid/OCL, BPP=HW/(TPB*RPT);
            zx_k<64,4,1><<<B*TcAct*nOcg*BPP, TPB, 0, s>>>(in,w,bias,zbuf,t0,TcAct,TcMax,B,T,Cin,Ctot,hid,H,W,nOcg,BPP); } break;
    }
}

static void launch_step(int l, const float* zbuf, const float* w,
                        float* hbuf, float* cbuf, int t, int tc, int TcMax,
                        int B, int T, int Cin, int hid, int H, int W, hipStream_t s)
{
    // every config -> exactly 512 blocks
    switch (l) {
        case 0: step_k<256,2,2,16><<<512,256,0,s>>>(zbuf,w,hbuf,cbuf,t,tc,TcMax,B,T,Cin,H,W, 8,8); break;
        case 1: step_k<128,2,2,32><<<512,128,0,s>>>(zbuf,w,hbuf,cbuf,t,tc,TcMax,B,T,Cin,H,W,16,4); break;
        case 2: step_k<128,2,1,64><<<512,128,0,s>>>(zbuf,w,hbuf,cbuf,t,tc,TcMax,B,T,Cin,H,W,32,2); break;
        case 3: step_k< 64,1,1,64><<<512, 64,0,s>>>(zbuf,w,hbuf,cbuf,t,tc,TcMax,B,T,Cin,H,W,64,1); break;
    }
}

extern "C" void kernel_launch(void* const* d_in, const int* in_sizes, int n_in,
                              void* d_out, int out_size, void* d_ws, size_t ws_size,
                              hipStream_t stream)
{
    const int B = 8, T = 40;
    const float* x = (const float*)d_in[0];

    // workspace layout (floats); ~141 MB total (proven available)
    float* hbuf  = (float*)d_ws;                 // 20,971,520
    float* pbuf  = hbuf + (size_t)20971520;      //  5,242,880
    float* cbuf  = pbuf + (size_t)5242880;       //    524,288
    float* stats = cbuf + (size_t)524288;        //        128
    float* zbuf  = stats + 128;                  //  8,388,608

    struct LCfg { int Cin, hid, H, W, Tc; };
    const LCfg L[4] = { {1, 16, 64, 64, 4}, {16, 32, 32, 32, 8},
                        {32, 64, 16, 16, 16}, {64, 64, 8, 8, 40} };

    const float* in = x;
    for (int l = 0; l < 4; ++l) {
        const float* w     = (const float*)d_in[1 + 4 * l];
        const float* bias  = (const float*)d_in[2 + 4 * l];
        const float* gamma = (const float*)d_in[3 + 4 * l];
        const float* beta  = (const float*)d_in[4 + 4 * l];
        const int Cin = L[l].Cin, hid = L[l].hid, H = L[l].H, W = L[l].W;
        const int HW = H * W;
        const int TcMax = L[l].Tc;

        for (int t0 = 0; t0 < T; t0 += TcMax) {
            int TcAct = (T - t0 < TcMax) ? (T - t0) : TcMax;
            launch_zx(l, in, w, bias, zbuf, t0, TcAct, TcMax, B, T, Cin, hid, H, W, stream);
            for (int t = t0; t < t0 + TcAct; ++t)
                launch_step(l, zbuf, w, hbuf, cbuf, t, t - t0, TcMax,
                            B, T, Cin, hid, H, W, stream);
        }

        hipMemsetAsync(stats, 0, 2 * hid * sizeof(float), stream);
        bn_stats<<<dim3(hid, 80), 256, 0, stream>>>(hbuf, stats, B * T, hid, HW);

        int ptotal = B * T * hid * (H / 2) * (W / 2);
        float invN = 1.0f / ((float)(B * T) * (float)HW);
        bn_relu_pool<<<(ptotal + 255) / 256, 256, 0, stream>>>(
            hbuf, stats, gamma, beta, pbuf, B * T, hid, H, W, invN);
        in = pbuf;
    }

    const float* fc1w = (const float*)d_in[17];
    const float* fc1b = (const float*)d_in[18];
    const float* fc2w = (const float*)d_in[19];
    const float* fc2b = (const float*)d_in[20];
    fc_head<<<B * T, 128, 0, stream>>>(pbuf, fc1w, fc1b, fc2w, fc2b, (float*)d_out);
}